// Round 12
// baseline (1092.036 us; speedup 1.0000x reference)
//
#include <hip/hip_runtime.h>
#include <hip/hip_cooperative_groups.h>
#include <math.h>

namespace cg = cooperative_groups;

#define BN_EPS 1e-5f
#define SLOT 96              // padded CSR slots per node (avg deg ~17)
#define LN16 2.7725887f      // exp bias: packed-fp16 accumulators stay finite

typedef _Float16 h2 __attribute__((ext_vector_type(2)));
typedef _Float16 h8 __attribute__((ext_vector_type(8)));
typedef float f2v __attribute__((ext_vector_type(2)));
typedef float float4v __attribute__((ext_vector_type(4)));

static __device__ inline h2 bit_h2(unsigned u) {
    union { unsigned u; h2 h; } c; c.u = u; return c.h;
}
static __device__ inline unsigned bit_u(h2 h) {
    union { unsigned u; h2 h; } c; c.h = h; return c.u;
}

// DPP partial-sum adds (VALU pipe, no LDS traffic).
template <int CTRL>
static __device__ inline float dpp_add(float x) {
    int y = __builtin_amdgcn_update_dpp(0, __float_as_int(x), CTRL, 0xF, 0xF, true);
    return x + __int_as_float(y);
}
static __device__ inline float red8_dpp(float t) {
    t = dpp_add<0xB1>(t); t = dpp_add<0x4E>(t); t = dpp_add<0x141>(t);
    return t;
}
static __device__ inline float red16_dpp(float t) {
    t = dpp_add<0xB1>(t); t = dpp_add<0x4E>(t); t = dpp_add<0x141>(t);
    t = dpp_add<0x140>(t);
    return t;
}

// ---------------------------------------------------------------------------
// All pointers/sizes in one struct (single cooperative kernel arg)
// ---------------------------------------------------------------------------
struct P {
    const int* src; const int* dst; int E; int Etot; int N;
    const float* x;
    const float* w1s; const float* w1d; const float* r0w; const float* r0b;
    const float* att1; const float* b1;
    const float* bn1g; const float* bn1b; const float* bn1m; const float* bn1v;
    const float* w2s; const float* w2d;
    const float* att2; const float* b2;
    const float* bn2g; const float* bn2b; const float* bn2m; const float* bn2v;
    const float* w3s; const float* w3d; const float* r2w; const float* r2b;
    const float* att3; const float* b3;
    const float* bn3g; const float* bn3b; const float* bn3m; const float* bn3v;
    _Float16* XLR; float* RES; _Float16* A;
    _Float16* Wb1; _Float16* Wb2; _Float16* Wb3;
    int* cnt; int* esrc;
    float* out;
};

// ---------------------------------------------------------------------------
// Weight packing: [p0|p1|p2] -> MFMA B-fragment-major fp16.
// ---------------------------------------------------------------------------
static __device__ inline void pack_one(int idx,
                                       const float* p0, const float* p1,
                                       const float* p2,
                                       int w0, int w1, int w2,
                                       int Ksrc, int Ncat,
                                       _Float16* out) {
    int k = idx / Ncat, n = idx - k * Ncat;
    float v = 0.f;
    if (k < Ksrc) {
        if (n < w0) v = p0[(size_t)k * w0 + n];
        else if (n < w0 + w1) v = p1[(size_t)k * w1 + (n - w0)];
        else if (w2 > 0 && n < w0 + w1 + w2) v = p2[(size_t)k * w2 + (n - w0 - w1)];
    }
    int kt = k >> 5, kr = k & 31;
    int quad = kr >> 3, j = kr & 7;
    int nt = n >> 4, nr = n & 15;
    int ntiles = Ncat >> 4;
    out[((size_t)(kt * ntiles + nt) * 64 + quad * 16 + nr) * 8 + j] = (_Float16)v;
}

// ---------------------------------------------------------------------------
// MFMA fp16 GEMM phase (grid-stride over waves). Kpad = 128.
// ---------------------------------------------------------------------------
template <int NT>
static __device__ void gemm_phase(const _Float16* __restrict__ A,
                                  const _Float16* __restrict__ Bp,
                                  _Float16* __restrict__ XLR,
                                  float* __restrict__ RES,
                                  int M, int Ncat, int ncat_valid, int res_off,
                                  int bf_remap, int bf_shift,
                                  int bf_stride, int res_stride) {
    int lane = threadIdx.x & 63;
    int gw = blockIdx.x * 4 + (threadIdx.x >> 6);
    int gws = gridDim.x * 4;
    int ngroups = Ncat / (16 * NT);
    int mtiles = M >> 4;
    int ntiles = Ncat >> 4;
    int quad = lane >> 4;
    int nr = lane & 15;
    for (int w = gw; w < mtiles * ngroups; w += gws) {
        int mt = w / ngroups;
        int ng = w - mt * ngroups;
        int row = mt * 16 + nr;
        float4v acc[NT];
#pragma unroll
        for (int t = 0; t < NT; t++) acc[t] = (float4v){0.f, 0.f, 0.f, 0.f};
#pragma unroll
        for (int k0 = 0; k0 < 128; k0 += 32) {
            h8 a = *(const h8*)(A + (size_t)row * 128 + k0 + quad * 8);
            int kt = k0 >> 5;
            const _Float16* bbase =
                Bp + ((size_t)(kt * ntiles + ng * NT) * 64 + lane) * 8;
#pragma unroll
            for (int t = 0; t < NT; t++) {
                h8 b = *(const h8*)(bbase + (size_t)t * 512);
                acc[t] = __builtin_amdgcn_mfma_f32_16x16x32_f16(a, b, acc[t], 0, 0, 0);
            }
        }
        int rowb = mt * 16 + quad * 4;
#pragma unroll
        for (int t = 0; t < NT; t++) {
            int col = (ng * NT + t) * 16 + nr;
            if (col >= ncat_valid) continue;
            if (col < res_off) {
                int bc = (col >= bf_remap) ? col + bf_shift : col;
#pragma unroll
                for (int r = 0; r < 4; r++)
                    XLR[(size_t)(rowb + r) * bf_stride + bc] = (_Float16)acc[t][r];
            } else {
                int rc = col - res_off;
#pragma unroll
                for (int r = 0; r < 4; r++)
                    RES[(size_t)(rowb + r) * res_stride + rc] = acc[t][r];
            }
        }
    }
}

// ---------------------------------------------------------------------------
// agg4 phase (H=4, C=32): grid-stride over nodes; one wave per node.
// ---------------------------------------------------------------------------
static __device__ void agg4_phase(const P& p, const float* __restrict__ att,
                                  const float* __restrict__ RES,
                                  const float* __restrict__ resB,
                                  const float* __restrict__ bias,
                                  const float* __restrict__ g,
                                  const float* __restrict__ bb,
                                  const float* __restrict__ mm,
                                  const float* __restrict__ vv, int mode) {
    int gw = blockIdx.x * 4 + (threadIdx.x >> 6);
    int gws = gridDim.x * 4;
    int lane = threadIdx.x & 63;
    int half = lane >> 5;
    int gl = lane & 31;
    int c0 = gl * 4;
    const char* xb = (const char*)p.XLR + c0 * 2;
    const h2 NS = {(_Float16)0.2f, (_Float16)0.2f};

    float4 af = *(const float4*)(att + c0);
    h2 at01 = {(_Float16)af.x, (_Float16)af.y};
    h2 at23 = {(_Float16)af.z, (_Float16)af.w};
    float4 bi = *(const float4*)(bias + c0);
    float4 gm = *(const float4*)(mm + c0);
    float4 gv = *(const float4*)(vv + c0);
    float4 gg = *(const float4*)(g + c0);
    float4 gb = *(const float4*)(bb + c0);
    float4 rb = (mode == 1) ? *(const float4*)(resB + c0)
                            : (float4){0.f, 0.f, 0.f, 0.f};
    float rs0 = rsqrtf(gv.x + BN_EPS), rs1 = rsqrtf(gv.y + BN_EPS);
    float rs2 = rsqrtf(gv.z + BN_EPS), rs3 = rsqrtf(gv.w + BN_EPS);

    for (int d = gw; d < p.N; d += gws) {
        uint2 xrv = *(const uint2*)(xb + (size_t)d * 512 + 256);
        h2 xr01 = bit_h2(xrv.x), xr23 = bit_h2(xrv.y);
        int beg = d * SLOT;
        int end = beg + p.cnt[d];
        float den = 0.f;
        h2 acc01 = {(_Float16)0.f, (_Float16)0.f};
        h2 acc23 = acc01;
        int j = beg;
        for (; j + 4 <= end; j += 4) {
            int o0 = p.esrc[j + half];
            int o1 = p.esrc[j + 2 + half];
            uint2 u0 = *(const uint2*)(xb + o0);
            uint2 u1 = *(const uint2*)(xb + o1);
            h2 a01 = bit_h2(u0.x), a23 = bit_h2(u0.y);
            h2 b01 = bit_h2(u1.x), b23 = bit_h2(u1.y);
            h2 v01 = a01 + xr01, v23 = a23 + xr23;
            h2 w01 = b01 + xr01, w23 = b23 + xr23;
            v01 = __builtin_elementwise_max(v01, v01 * NS);
            v23 = __builtin_elementwise_max(v23, v23 * NS);
            w01 = __builtin_elementwise_max(w01, w01 * NS);
            w23 = __builtin_elementwise_max(w23, w23 * NS);
            h2 t2a = v01 * at01 + v23 * at23;
            h2 t2b = w01 * at01 + w23 * at23;
            f2v ta = __builtin_convertvector(t2a, f2v);
            f2v tb = __builtin_convertvector(t2b, f2v);
            float t0 = red8_dpp(ta.x + ta.y);
            float t1 = red8_dpp(tb.x + tb.y);
            float p0 = __expf(t0 - LN16);
            float p1 = __expf(t1 - LN16);
            den += p0 + p1;
            h2 P0 = {(_Float16)p0, (_Float16)p0};
            h2 P1 = {(_Float16)p1, (_Float16)p1};
            acc01 = P0 * a01 + acc01;
            acc23 = P0 * a23 + acc23;
            acc01 = P1 * b01 + acc01;
            acc23 = P1 * b23 + acc23;
        }
        for (; j < end; j += 2) {
            int jj = j + half;
            bool act = jj < end;
            int o = p.esrc[act ? jj : (end - 1)];
            uint2 u0 = *(const uint2*)(xb + o);
            h2 a01 = bit_h2(u0.x), a23 = bit_h2(u0.y);
            h2 v01 = a01 + xr01, v23 = a23 + xr23;
            v01 = __builtin_elementwise_max(v01, v01 * NS);
            v23 = __builtin_elementwise_max(v23, v23 * NS);
            h2 t2 = v01 * at01 + v23 * at23;
            f2v tf = __builtin_convertvector(t2, f2v);
            float t = red8_dpp(tf.x + tf.y);
            float pp = act ? __expf(t - LN16) : 0.f;
            den += pp;
            h2 PP = {(_Float16)pp, (_Float16)pp};
            acc01 = PP * a01 + acc01;
            acc23 = PP * a23 + acc23;
        }
        den += __shfl_xor(den, 32);
        f2v c01 = __builtin_convertvector(acc01, f2v);
        f2v c23 = __builtin_convertvector(acc23, f2v);
        float f0 = c01.x, f1 = c01.y, fA = c23.x, fB = c23.y;
        f0 += __shfl_xor(f0, 32);
        f1 += __shfl_xor(f1, 32);
        fA += __shfl_xor(fA, 32);
        fB += __shfl_xor(fB, 32);

        if (half == 0) {
            float inv = 1.f / den;
            float o0 = f0 * inv + bi.x;
            float o1 = f1 * inv + bi.y;
            float o2 = fA * inv + bi.z;
            float o3 = fB * inv + bi.w;
            if (mode == 1) {
                float4 r = *(const float4*)(RES + (size_t)d * 128 + c0);
                o0 += r.x + rb.x; o1 += r.y + rb.y;
                o2 += r.z + rb.z; o3 += r.w + rb.w;
            } else {
                uint2 hv = *(const uint2*)(p.A + (size_t)d * 128 + c0);
                f2v g01 = __builtin_convertvector(bit_h2(hv.x), f2v);
                f2v g23 = __builtin_convertvector(bit_h2(hv.y), f2v);
                o0 += g01.x; o1 += g01.y; o2 += g23.x; o3 += g23.y;
            }
            o0 = fmaxf((o0 - gm.x) * rs0 * gg.x + gb.x, 0.f);
            o1 = fmaxf((o1 - gm.y) * rs1 * gg.y + gb.y, 0.f);
            o2 = fmaxf((o2 - gm.z) * rs2 * gg.z + gb.z, 0.f);
            o3 = fmaxf((o3 - gm.w) * rs3 * gg.w + gb.w, 0.f);
            h2 s01 = {(_Float16)o0, (_Float16)o1};
            h2 s23 = {(_Float16)o2, (_Float16)o3};
            uint2 w;
            w.x = bit_u(s01);
            w.y = bit_u(s23);
            *(uint2*)(p.A + (size_t)d * 128 + c0) = w;
        }
    }
}

// ---------------------------------------------------------------------------
// agg1 phase (H=1, C=47, layer 3): grid-stride over nodes.
// ---------------------------------------------------------------------------
static __device__ void agg1_phase(const P& p) {
    int gw = blockIdx.x * 4 + (threadIdx.x >> 6);
    int gws = gridDim.x * 4;
    int lane = threadIdx.x & 63;
    int gl = lane & 15, grp = lane >> 4;
    const char* xb = (const char*)p.XLR + gl * 8;
    const h2 NS = {(_Float16)0.2f, (_Float16)0.2f};

    float atf[4];
#pragma unroll
    for (int k = 0; k < 4; k++) {
        int c = gl * 4 + k;
        atf[k] = (c < 47) ? p.att3[c] : 0.f;
    }
    h2 at01 = {(_Float16)atf[0], (_Float16)atf[1]};
    h2 at23 = {(_Float16)atf[2], (_Float16)atf[3]};

    for (int d = gw; d < p.N; d += gws) {
        uint2 xrv = *(const uint2*)(xb + (size_t)d * 256 + 128);
        h2 xr01 = bit_h2(xrv.x), xr23 = bit_h2(xrv.y);
        int beg = d * SLOT;
        int end = beg + p.cnt[d];
        float den = 0.f;
        h2 acc01 = {(_Float16)0.f, (_Float16)0.f};
        h2 acc23 = acc01;
        int j = beg + grp;
        for (; j + 4 < end; j += 8) {
            int o0 = p.esrc[j] >> 1;
            int o1 = p.esrc[j + 4] >> 1;
            uint2 u0 = *(const uint2*)(xb + o0);
            uint2 u1 = *(const uint2*)(xb + o1);
            h2 a01 = bit_h2(u0.x), a23 = bit_h2(u0.y);
            h2 b01 = bit_h2(u1.x), b23 = bit_h2(u1.y);
            h2 v01 = a01 + xr01, v23 = a23 + xr23;
            h2 w01 = b01 + xr01, w23 = b23 + xr23;
            v01 = __builtin_elementwise_max(v01, v01 * NS);
            v23 = __builtin_elementwise_max(v23, v23 * NS);
            w01 = __builtin_elementwise_max(w01, w01 * NS);
            w23 = __builtin_elementwise_max(w23, w23 * NS);
            h2 t2a = v01 * at01 + v23 * at23;
            h2 t2b = w01 * at01 + w23 * at23;
            f2v ta = __builtin_convertvector(t2a, f2v);
            f2v tb = __builtin_convertvector(t2b, f2v);
            float t0 = red16_dpp(ta.x + ta.y);
            float t1 = red16_dpp(tb.x + tb.y);
            float p0 = __expf(t0 - LN16);
            float p1 = __expf(t1 - LN16);
            den += p0 + p1;
            h2 P0 = {(_Float16)p0, (_Float16)p0};
            h2 P1 = {(_Float16)p1, (_Float16)p1};
            acc01 = P0 * a01 + acc01;
            acc23 = P0 * a23 + acc23;
            acc01 = P1 * b01 + acc01;
            acc23 = P1 * b23 + acc23;
        }
        if (j < end) {
            int o = p.esrc[j] >> 1;
            uint2 u0 = *(const uint2*)(xb + o);
            h2 a01 = bit_h2(u0.x), a23 = bit_h2(u0.y);
            h2 v01 = a01 + xr01, v23 = a23 + xr23;
            v01 = __builtin_elementwise_max(v01, v01 * NS);
            v23 = __builtin_elementwise_max(v23, v23 * NS);
            h2 t2 = v01 * at01 + v23 * at23;
            f2v tf = __builtin_convertvector(t2, f2v);
            float t = red16_dpp(tf.x + tf.y);
            float pp = __expf(t - LN16);
            den += pp;
            h2 PP = {(_Float16)pp, (_Float16)pp};
            acc01 = PP * a01 + acc01;
            acc23 = PP * a23 + acc23;
        }
        den += __shfl_xor(den, 16);
        den += __shfl_xor(den, 32);
        f2v c01 = __builtin_convertvector(acc01, f2v);
        f2v c23 = __builtin_convertvector(acc23, f2v);
        float f[4] = {c01.x, c01.y, c23.x, c23.y};
#pragma unroll
        for (int k = 0; k < 4; k++) {
            f[k] += __shfl_xor(f[k], 16);
            f[k] += __shfl_xor(f[k], 32);
        }
        if (grp == 0 && gl < 12) {
            float inv = 1.f / den;
#pragma unroll
            for (int k = 0; k < 4; k++) {
                int c = gl * 4 + k;
                if (c < 47) {
                    float o = f[k] * inv + p.b3[c] + p.RES[(size_t)d * 48 + c]
                              + p.r2b[c];
                    o = (o - p.bn3m[c]) * rsqrtf(p.bn3v[c] + BN_EPS) * p.bn3g[c]
                        + p.bn3b[c];
                    p.out[(size_t)d * 47 + c] = o;
                }
            }
        }
    }
}

// ---------------------------------------------------------------------------
// The whole network: one cooperative kernel, 7 phases, 6 grid syncs.
// ---------------------------------------------------------------------------
__global__ __launch_bounds__(256, 4) void fused_k(P p) {
    cg::grid_group grid = cg::this_grid();
    int tid = blockIdx.x * 256 + threadIdx.x;
    int gs = gridDim.x * 256;

    // ---- phase A: zero cnt + conv x->A (fp16) + pack weights ----
    {
        const int S1 = 128 * 384, S2 = 128 * 256, S3 = 128 * 144;
        int convTot = p.N * 128;
        int tot = p.N + convTot + S1 + S2 + S3;
        for (int i = tid; i < tot; i += gs) {
            if (i < p.N) {
                p.cnt[i] = 0;
            } else if (i < p.N + convTot) {
                int idx = i - p.N;
                int n = idx >> 7, k = idx & 127;
                p.A[idx] = (_Float16)(k < 100 ? p.x[(size_t)n * 100 + k] : 0.f);
            } else {
                int q = i - p.N - convTot;
                if (q < S1) pack_one(q, p.w1s, p.w1d, p.r0w, 128, 128, 128, 100, 384, p.Wb1);
                else if (q < S1 + S2) pack_one(q - S1, p.w2s, p.w2d, nullptr, 128, 128, 0, 128, 256, p.Wb2);
                else pack_one(q - S1 - S2, p.w3s, p.w3d, p.r2w, 47, 47, 47, 128, 144, p.Wb3);
            }
        }
    }
    grid.sync();

    // ---- phase B: scatter (padded-slot CSR) + layer-1 GEMM ----
    for (int i = tid; i < p.Etot; i += gs) {
        int d = (i < p.E) ? p.dst[i] : (i - p.E);
        int s = (i < p.E) ? p.src[i] : (i - p.E);
        int pos = atomicAdd(&p.cnt[d], 1);
        p.esrc[(size_t)d * SLOT + pos] = s << 9;
    }
    gemm_phase<4>(p.A, p.Wb1, p.XLR, p.RES, p.N, 384, 384, 256, 384, 0, 256, 128);
    grid.sync();

    // ---- phase C: layer-1 agg + epilogue ----
    agg4_phase(p, p.att1, p.RES, p.r0b, p.b1, p.bn1g, p.bn1b, p.bn1m, p.bn1v, 1);
    grid.sync();

    // ---- phase D: layer-2 GEMM ----
    gemm_phase<4>(p.A, p.Wb2, p.XLR, p.RES, p.N, 256, 256, 256, 256, 0, 256, 128);
    grid.sync();

    // ---- phase E: layer-2 agg + epilogue ----
    agg4_phase(p, p.att2, nullptr, nullptr, p.b2, p.bn2g, p.bn2b, p.bn2m, p.bn2v, 2);
    grid.sync();

    // ---- phase F: layer-3 GEMM ----
    gemm_phase<3>(p.A, p.Wb3, p.XLR, p.RES, p.N, 144, 141, 94, 47, 17, 128, 48);
    grid.sync();

    // ---- phase G: layer-3 agg + epilogue ----
    agg1_phase(p);
}

// ---------------------------------------------------------------------------
extern "C" void kernel_launch(void* const* d_in, const int* in_sizes, int n_in,
                              void* d_out, int out_size, void* d_ws, size_t ws_size,
                              hipStream_t stream) {
    const int F_IN = 100;
    const int KP = 128;
    const int NC1 = 384, NC2 = 256, NC3 = 144;
    int N = in_sizes[0] / F_IN;
    int E = in_sizes[1] / 2;

    // ---- workspace layout (float units) ----
    float* ws = (float*)d_ws;
    size_t o = 0;
    _Float16* XLR = (_Float16*)(ws + o); o += (size_t)N * 128;   // [N,256] fp16
    float* B_res = ws + o; o += (size_t)N * 128;                 // residual fp32
    _Float16* A_h = (_Float16*)(ws + o); o += (size_t)N * 64;    // [N,128] fp16
    _Float16* Wb1 = (_Float16*)(ws + o); o += (size_t)KP * NC1 / 2;
    _Float16* Wb2 = (_Float16*)(ws + o); o += (size_t)KP * NC2 / 2;
    _Float16* Wb3 = (_Float16*)(ws + o); o += (size_t)KP * NC3 / 2;
    int* I_cnt  = (int*)(ws + o); o += N;
    int* I_esrc = (int*)(ws + o); o += (size_t)N * SLOT + 4;
    (void)ws_size; (void)n_in; (void)out_size;

    P p;
    p.src = (const int*)d_in[1];
    p.dst = (const int*)d_in[1] + E;
    p.E = E; p.Etot = E + N; p.N = N;
    p.x = (const float*)d_in[0];
    p.w1s = (const float*)d_in[2];  p.w1d = (const float*)d_in[3];
    p.att1 = (const float*)d_in[4]; p.b1 = (const float*)d_in[5];
    p.bn1g = (const float*)d_in[6]; p.bn1b = (const float*)d_in[7];
    p.bn1m = (const float*)d_in[8]; p.bn1v = (const float*)d_in[9];
    p.r0w = (const float*)d_in[10]; p.r0b = (const float*)d_in[11];
    p.w2s = (const float*)d_in[12]; p.w2d = (const float*)d_in[13];
    p.att2 = (const float*)d_in[14]; p.b2 = (const float*)d_in[15];
    p.bn2g = (const float*)d_in[16]; p.bn2b = (const float*)d_in[17];
    p.bn2m = (const float*)d_in[18]; p.bn2v = (const float*)d_in[19];
    p.w3s = (const float*)d_in[20]; p.w3d = (const float*)d_in[21];
    p.att3 = (const float*)d_in[22]; p.b3 = (const float*)d_in[23];
    p.bn3g = (const float*)d_in[24]; p.bn3b = (const float*)d_in[25];
    p.bn3m = (const float*)d_in[26]; p.bn3v = (const float*)d_in[27];
    p.r2w = (const float*)d_in[28]; p.r2b = (const float*)d_in[29];
    p.XLR = XLR; p.RES = B_res; p.A = A_h;
    p.Wb1 = Wb1; p.Wb2 = Wb2; p.Wb3 = Wb3;
    p.cnt = I_cnt; p.esrc = I_esrc;
    p.out = (float*)d_out;

    // Size the cooperative grid from the RUNTIME occupancy of fused_k —
    // never assume launch_bounds was honored (round-11 failure: hard-coded
    // 1024 blocks was rejected, kernel never ran). Query is a pure host call:
    // deterministic, stream-free, graph-capture-safe.
    int perCU = 0;
    hipError_t qerr = hipOccupancyMaxActiveBlocksPerMultiprocessor(
        &perCU, (const void*)fused_k, 256, 0);
    if (qerr != hipSuccess || perCU < 1) perCU = 1;
    if (perCU > 4) perCU = 4;          // 1024 blocks is plenty for grid-stride
    int nblk = perCU * 256;            // 256 CUs on MI355X

    void* args[] = { (void*)&p };
    hipLaunchCooperativeKernel((void*)fused_k, dim3(nblk), dim3(256), args, 0,
                               stream);
}

// Round 13
// 389.915 us; speedup vs baseline: 2.8007x; 2.8007x over previous
//
#include <hip/hip_runtime.h>
#include <math.h>

#define BN_EPS 1e-5f
#define SLOT 96              // padded CSR slots per node (avg deg ~17, P(>96)~0)
#define LN16 2.7725887f      // exp bias so packed-fp16 accumulators can't overflow

typedef _Float16 h2 __attribute__((ext_vector_type(2)));
typedef _Float16 h8 __attribute__((ext_vector_type(8)));
typedef float f2v __attribute__((ext_vector_type(2)));
typedef float float4v __attribute__((ext_vector_type(4)));

static __device__ inline h2 bit_h2(unsigned u) {
    union { unsigned u; h2 h; } c; c.u = u; return c.h;
}
static __device__ inline unsigned bit_u(h2 h) {
    union { unsigned u; h2 h; } c; c.h = h; return c.u;
}

// DPP partial-sum adds (VALU pipe). 0xB1=quad xor1, 0x4E=quad xor2,
// 0x141=row_half_mirror (8-lane), 0x140=row_mirror (16-lane).
template <int CTRL>
static __device__ inline float dpp_add(float x) {
    int y = __builtin_amdgcn_update_dpp(0, __float_as_int(x), CTRL, 0xF, 0xF, true);
    return x + __int_as_float(y);
}
static __device__ inline float red8_dpp(float t) {
    t = dpp_add<0xB1>(t); t = dpp_add<0x4E>(t); t = dpp_add<0x141>(t);
    return t;
}
static __device__ inline float red16_dpp(float t) {
    t = dpp_add<0xB1>(t); t = dpp_add<0x4E>(t); t = dpp_add<0x141>(t);
    t = dpp_add<0x140>(t);
    return t;
}

// ---------------------------------------------------------------------------
// Weight packing: [p0|p1|p2] -> MFMA B-fragment-major fp16.
// ---------------------------------------------------------------------------
static __device__ inline void pack_one(int idx,
                                       const float* p0, const float* p1,
                                       const float* p2,
                                       int w0, int w1, int w2,
                                       int Ksrc, int Ncat,
                                       _Float16* out) {
    int k = idx / Ncat, n = idx - k * Ncat;
    float v = 0.f;
    if (k < Ksrc) {
        if (n < w0) v = p0[(size_t)k * w0 + n];
        else if (n < w0 + w1) v = p1[(size_t)k * w1 + (n - w0)];
        else if (w2 > 0 && n < w0 + w1 + w2) v = p2[(size_t)k * w2 + (n - w0 - w1)];
    }
    int kt = k >> 5, kr = k & 31;
    int quad = kr >> 3, j = kr & 7;
    int nt = n >> 4, nr = n & 15;
    int ntiles = Ncat >> 4;
    out[((size_t)(kt * ntiles + nt) * 64 + quad * 16 + nr) * 8 + j] = (_Float16)v;
}

// ---------------------------------------------------------------------------
// prep + scatter grid-stuffed. Scatter: padded-slot CSR, byte offsets (s*512)
// via non-temporal stores (random 4B writes -> avoid line write-allocate).
// Prep: x fp32 -> A fp16 [N,128] zero-padded; pack 3 weight tensors.
// ---------------------------------------------------------------------------
__global__ __launch_bounds__(256) void prep_scat_k(
    const int* __restrict__ src, const int* __restrict__ dst, int E, int Etot,
    int* __restrict__ cnt, int* __restrict__ esrc, int scatBlocks,
    const float* __restrict__ x, _Float16* __restrict__ A, int N,
    const float* __restrict__ w1s, const float* __restrict__ w1d,
    const float* __restrict__ r0w, const float* __restrict__ w2s,
    const float* __restrict__ w2d, const float* __restrict__ w3s,
    const float* __restrict__ w3d, const float* __restrict__ r2w,
    _Float16* __restrict__ Wb1, _Float16* __restrict__ Wb2,
    _Float16* __restrict__ Wb3) {
    if ((int)blockIdx.x < scatBlocks) {
        int i = blockIdx.x * 256 + threadIdx.x;
        if (i < Etot) {
            int d = (i < E) ? dst[i] : (i - E);
            int s = (i < E) ? src[i] : (i - E);
            int pos = atomicAdd(&cnt[d], 1);
            __builtin_nontemporal_store(s << 9, &esrc[(size_t)d * SLOT + pos]);
        }
        return;
    }
    const int S1 = 128 * 384, S2 = 128 * 256, S3 = 128 * 144;
    int convTot = N * 128;
    int idx = (blockIdx.x - scatBlocks) * 256 + threadIdx.x;
    if (idx < convTot) {
        int n = idx >> 7, k = idx & 127;
        A[idx] = (_Float16)(k < 100 ? x[(size_t)n * 100 + k] : 0.f);
        return;
    }
    int p = idx - convTot;
    if (p < S1) pack_one(p, w1s, w1d, r0w, 128, 128, 128, 100, 384, Wb1);
    else if (p < S1 + S2) pack_one(p - S1, w2s, w2d, nullptr, 128, 128, 0, 128, 256, Wb2);
    else if (p < S1 + S2 + S3) pack_one(p - S1 - S2, w3s, w3d, r2w, 47, 47, 47, 128, 144, Wb3);
}

// ---------------------------------------------------------------------------
// MFMA fp16 GEMM, A-resident: one wave = one 16-row tile x ALL columns.
// A fragments (4 x h8 = whole K=128 strip) loaded ONCE into registers, then
// loop over column groups -> A traffic cut by ngroups x vs per-group waves.
// cols < res_off -> fp16 into XLR (col >= bf_remap shifted +bf_shift);
// cols in [res_off, ncat_valid) -> fp32 into RES; rest dropped.
// ---------------------------------------------------------------------------
template <int NT>
__global__ __launch_bounds__(256) void mfma_gemm(const _Float16* __restrict__ A,
                                                 const _Float16* __restrict__ Bp,
                                                 _Float16* __restrict__ XLR,
                                                 float* __restrict__ RES,
                                                 int M, int Ncat,
                                                 int ncat_valid, int res_off,
                                                 int bf_remap, int bf_shift,
                                                 int bf_stride, int res_stride) {
    int mt = (blockIdx.x * 256 + threadIdx.x) >> 6;
    int lane = threadIdx.x & 63;
    int mtiles = M >> 4;
    if (mt >= mtiles) return;
    int ngroups = Ncat / (16 * NT);
    int ntiles = Ncat >> 4;
    int quad = lane >> 4;
    int nr = lane & 15;
    int row = mt * 16 + nr;

    // whole-K A strip in registers (loaded once)
    h8 a[4];
#pragma unroll
    for (int kt = 0; kt < 4; kt++)
        a[kt] = *(const h8*)(A + (size_t)row * 128 + kt * 32 + quad * 8);

    int rowb = mt * 16 + quad * 4;
    for (int ng = 0; ng < ngroups; ng++) {
        float4v acc[NT];
#pragma unroll
        for (int t = 0; t < NT; t++) acc[t] = (float4v){0.f, 0.f, 0.f, 0.f};
#pragma unroll
        for (int kt = 0; kt < 4; kt++) {
            const _Float16* bbase =
                Bp + ((size_t)(kt * ntiles + ng * NT) * 64 + lane) * 8;
#pragma unroll
            for (int t = 0; t < NT; t++) {
                h8 b = *(const h8*)(bbase + (size_t)t * 512);
                acc[t] = __builtin_amdgcn_mfma_f32_16x16x32_f16(a[kt], b, acc[t], 0, 0, 0);
            }
        }
#pragma unroll
        for (int t = 0; t < NT; t++) {
            int col = (ng * NT + t) * 16 + nr;
            if (col >= ncat_valid) continue;
            if (col < res_off) {
                int bc = (col >= bf_remap) ? col + bf_shift : col;
#pragma unroll
                for (int r = 0; r < 4; r++)
                    XLR[(size_t)(rowb + r) * bf_stride + bc] = (_Float16)acc[t][r];
            } else {
                int rc = col - res_off;
#pragma unroll
                for (int r = 0; r < 4; r++)
                    RES[(size_t)(rowb + r) * res_stride + rc] = acc[t][r];
            }
        }
    }
}

// ---------------------------------------------------------------------------
// Fused GATv2 agg + epilogue, H=4 C=32. One wave per dst node; half-wave edge
// pairs; lane owns 4 channels as 2 packed fp16 pairs; 4 gathers in flight
// (8 edges per unrolled iteration); DPP 8-lane reduce; exp biased by -ln16.
// esrc = byte offsets. XLR rows 512 B: xl @0, xr @256.
// mode 1: h = relu(BN(agg + bias + RES + resB))     -> hbf fp16
// mode 2: h = relu(BN(agg + bias + fp16(hbf_prev))) -> hbf in-place
// ---------------------------------------------------------------------------
__global__ __launch_bounds__(256) void gat_agg4_fused(
    const int* __restrict__ cnt, const int* __restrict__ esrc,
    const _Float16* __restrict__ xlr, const float* __restrict__ att,
    const float* __restrict__ RES, const float* __restrict__ resB,
    const float* __restrict__ bias,
    const float* __restrict__ g, const float* __restrict__ bb,
    const float* __restrict__ mm, const float* __restrict__ vv,
    _Float16* __restrict__ hbf, int N, int mode) {
    int d = blockIdx.x * 4 + (threadIdx.x >> 6);
    if (d >= N) return;
    int lane = threadIdx.x & 63;
    int half = lane >> 5;
    int gl = lane & 31;
    int c0 = gl * 4;
    const char* xb = (const char*)xlr + c0 * 2;
    const h2 NS = {(_Float16)0.2f, (_Float16)0.2f};

    uint2 xrv = *(const uint2*)(xb + (size_t)d * 512 + 256);
    h2 xr01 = bit_h2(xrv.x), xr23 = bit_h2(xrv.y);
    float4 af = *(const float4*)(att + c0);
    h2 at01 = {(_Float16)af.x, (_Float16)af.y};
    h2 at23 = {(_Float16)af.z, (_Float16)af.w};

    int beg = d * SLOT;
    int end = beg + cnt[d];
    float den = 0.f;
    h2 acc01 = {(_Float16)0.f, (_Float16)0.f};
    h2 acc23 = acc01;
    int j = beg;
    // 8 edges per iteration: 4 gathers in flight per lane
    for (; j + 8 <= end; j += 8) {
        uint2 u[4];
#pragma unroll
        for (int q = 0; q < 4; q++) {
            int o = esrc[j + 2 * q + half];
            u[q] = *(const uint2*)(xb + o);
        }
#pragma unroll
        for (int q = 0; q < 4; q++) {
            h2 a01 = bit_h2(u[q].x), a23 = bit_h2(u[q].y);
            h2 v01 = a01 + xr01, v23 = a23 + xr23;
            v01 = __builtin_elementwise_max(v01, v01 * NS);
            v23 = __builtin_elementwise_max(v23, v23 * NS);
            h2 t2 = v01 * at01 + v23 * at23;
            f2v tf = __builtin_convertvector(t2, f2v);
            float t = red8_dpp(tf.x + tf.y);
            float p = __expf(t - LN16);
            den += p;
            h2 P = {(_Float16)p, (_Float16)p};
            acc01 = P * a01 + acc01;
            acc23 = P * a23 + acc23;
        }
    }
    for (; j < end; j += 2) {
        int jj = j + half;
        bool act = jj < end;
        int o = esrc[act ? jj : (end - 1)];
        uint2 u0 = *(const uint2*)(xb + o);
        h2 a01 = bit_h2(u0.x), a23 = bit_h2(u0.y);
        h2 v01 = a01 + xr01, v23 = a23 + xr23;
        v01 = __builtin_elementwise_max(v01, v01 * NS);
        v23 = __builtin_elementwise_max(v23, v23 * NS);
        h2 t2 = v01 * at01 + v23 * at23;
        f2v tf = __builtin_convertvector(t2, f2v);
        float t = red8_dpp(tf.x + tf.y);
        float p = act ? __expf(t - LN16) : 0.f;
        den += p;
        h2 P = {(_Float16)p, (_Float16)p};
        acc01 = P * a01 + acc01;
        acc23 = P * a23 + acc23;
    }
    den += __shfl_xor(den, 32);
    f2v c01 = __builtin_convertvector(acc01, f2v);
    f2v c23 = __builtin_convertvector(acc23, f2v);
    float f0 = c01.x, f1 = c01.y, fA = c23.x, fB = c23.y;
    f0 += __shfl_xor(f0, 32);
    f1 += __shfl_xor(f1, 32);
    fA += __shfl_xor(fA, 32);
    fB += __shfl_xor(fB, 32);

    if (half == 0) {
        float inv = 1.f / den;
        float4 bi = *(const float4*)(bias + c0);
        float o0 = f0 * inv + bi.x;
        float o1 = f1 * inv + bi.y;
        float o2 = fA * inv + bi.z;
        float o3 = fB * inv + bi.w;
        if (mode == 1) {
            float4 r = *(const float4*)(RES + (size_t)d * 128 + c0);
            float4 rb = *(const float4*)(resB + c0);
            o0 += r.x + rb.x; o1 += r.y + rb.y;
            o2 += r.z + rb.z; o3 += r.w + rb.w;
        } else {
            uint2 hv = *(const uint2*)(hbf + (size_t)d * 128 + c0);
            f2v g01 = __builtin_convertvector(bit_h2(hv.x), f2v);
            f2v g23 = __builtin_convertvector(bit_h2(hv.y), f2v);
            o0 += g01.x; o1 += g01.y; o2 += g23.x; o3 += g23.y;
        }
        float4 gm = *(const float4*)(mm + c0);
        float4 gv = *(const float4*)(vv + c0);
        float4 gg = *(const float4*)(g + c0);
        float4 gb = *(const float4*)(bb + c0);
        o0 = fmaxf((o0 - gm.x) * rsqrtf(gv.x + BN_EPS) * gg.x + gb.x, 0.f);
        o1 = fmaxf((o1 - gm.y) * rsqrtf(gv.y + BN_EPS) * gg.y + gb.y, 0.f);
        o2 = fmaxf((o2 - gm.z) * rsqrtf(gv.z + BN_EPS) * gg.z + gb.z, 0.f);
        o3 = fmaxf((o3 - gm.w) * rsqrtf(gv.w + BN_EPS) * gg.w + gb.w, 0.f);
        h2 s01 = {(_Float16)o0, (_Float16)o1};
        h2 s23 = {(_Float16)o2, (_Float16)o3};
        uint2 w;
        w.x = bit_u(s01);
        w.y = bit_u(s23);
        *(uint2*)(hbf + (size_t)d * 128 + c0) = w;
    }
}

// ---------------------------------------------------------------------------
// Fused GATv2 agg + epilogue, H=1 C=47 (layer 3). 16-lane edge groups,
// unroll-2, packed fp16 math, DPP 16-lane reduce. esrc byte offsets (>>1 for
// 256 B rows). XLR rows of 128 fp16: xl @0..47(pad), xr @64..111(pad).
// out = BN(agg + b3 + RES + res2_b), no relu.
// ---------------------------------------------------------------------------
__global__ __launch_bounds__(256) void gat_agg1_fused(
    const int* __restrict__ cnt, const int* __restrict__ esrc,
    const _Float16* __restrict__ xlr, const float* __restrict__ att,
    const float* __restrict__ RES, const float* __restrict__ resB,
    const float* __restrict__ bias,
    const float* __restrict__ g, const float* __restrict__ bb,
    const float* __restrict__ mm, const float* __restrict__ vv,
    float* __restrict__ out, int N) {
    int d = blockIdx.x * 4 + (threadIdx.x >> 6);
    if (d >= N) return;
    int lane = threadIdx.x & 63;
    int gl = lane & 15, grp = lane >> 4;
    const char* xb = (const char*)xlr + gl * 8;
    const h2 NS = {(_Float16)0.2f, (_Float16)0.2f};

    uint2 xrv = *(const uint2*)(xb + (size_t)d * 256 + 128);
    h2 xr01 = bit_h2(xrv.x), xr23 = bit_h2(xrv.y);
    float atf[4];
#pragma unroll
    for (int k = 0; k < 4; k++) {
        int c = gl * 4 + k;
        atf[k] = (c < 47) ? att[c] : 0.f;
    }
    h2 at01 = {(_Float16)atf[0], (_Float16)atf[1]};
    h2 at23 = {(_Float16)atf[2], (_Float16)atf[3]};

    int beg = d * SLOT;
    int end = beg + cnt[d];
    float den = 0.f;
    h2 acc01 = {(_Float16)0.f, (_Float16)0.f};
    h2 acc23 = acc01;
    int j = beg + grp;
    for (; j + 4 < end; j += 8) {
        int o0 = esrc[j] >> 1;
        int o1 = esrc[j + 4] >> 1;
        uint2 u0 = *(const uint2*)(xb + o0);
        uint2 u1 = *(const uint2*)(xb + o1);
        h2 a01 = bit_h2(u0.x), a23 = bit_h2(u0.y);
        h2 b01 = bit_h2(u1.x), b23 = bit_h2(u1.y);
        h2 v01 = a01 + xr01, v23 = a23 + xr23;
        h2 w01 = b01 + xr01, w23 = b23 + xr23;
        v01 = __builtin_elementwise_max(v01, v01 * NS);
        v23 = __builtin_elementwise_max(v23, v23 * NS);
        w01 = __builtin_elementwise_max(w01, w01 * NS);
        w23 = __builtin_elementwise_max(w23, w23 * NS);
        h2 t2a = v01 * at01 + v23 * at23;
        h2 t2b = w01 * at01 + w23 * at23;
        f2v ta = __builtin_convertvector(t2a, f2v);
        f2v tb = __builtin_convertvector(t2b, f2v);
        float t0 = red16_dpp(ta.x + ta.y);
        float t1 = red16_dpp(tb.x + tb.y);
        float p0 = __expf(t0 - LN16);
        float p1 = __expf(t1 - LN16);
        den += p0 + p1;
        h2 P0 = {(_Float16)p0, (_Float16)p0};
        h2 P1 = {(_Float16)p1, (_Float16)p1};
        acc01 = P0 * a01 + acc01;
        acc23 = P0 * a23 + acc23;
        acc01 = P1 * b01 + acc01;
        acc23 = P1 * b23 + acc23;
    }
    if (j < end) {
        int o = esrc[j] >> 1;
        uint2 u0 = *(const uint2*)(xb + o);
        h2 a01 = bit_h2(u0.x), a23 = bit_h2(u0.y);
        h2 v01 = a01 + xr01, v23 = a23 + xr23;
        v01 = __builtin_elementwise_max(v01, v01 * NS);
        v23 = __builtin_elementwise_max(v23, v23 * NS);
        h2 t2 = v01 * at01 + v23 * at23;
        f2v tf = __builtin_convertvector(t2, f2v);
        float t = red16_dpp(tf.x + tf.y);
        float p = __expf(t - LN16);
        den += p;
        h2 P = {(_Float16)p, (_Float16)p};
        acc01 = P * a01 + acc01;
        acc23 = P * a23 + acc23;
    }
    den += __shfl_xor(den, 16);
    den += __shfl_xor(den, 32);
    f2v c01 = __builtin_convertvector(acc01, f2v);
    f2v c23 = __builtin_convertvector(acc23, f2v);
    float f[4] = {c01.x, c01.y, c23.x, c23.y};
#pragma unroll
    for (int k = 0; k < 4; k++) {
        f[k] += __shfl_xor(f[k], 16);
        f[k] += __shfl_xor(f[k], 32);
    }
    if (grp == 0 && gl < 12) {
        float inv = 1.f / den;
#pragma unroll
        for (int k = 0; k < 4; k++) {
            int c = gl * 4 + k;
            if (c < 47) {
                float o = f[k] * inv + bias[c] + RES[(size_t)d * 48 + c] + resB[c];
                o = (o - mm[c]) * rsqrtf(vv[c] + BN_EPS) * g[c] + bb[c];
                out[(size_t)d * 47 + c] = o;
            }
        }
    }
}

// ---------------------------------------------------------------------------
extern "C" void kernel_launch(void* const* d_in, const int* in_sizes, int n_in,
                              void* d_out, int out_size, void* d_ws, size_t ws_size,
                              hipStream_t stream) {
    const float* x      = (const float*)d_in[0];
    const int*   ei     = (const int*)d_in[1];
    const float* w1_src = (const float*)d_in[2];
    const float* w1_dst = (const float*)d_in[3];
    const float* att1   = (const float*)d_in[4];
    const float* b1     = (const float*)d_in[5];
    const float* bn1_g  = (const float*)d_in[6];
    const float* bn1_b  = (const float*)d_in[7];
    const float* bn1_m  = (const float*)d_in[8];
    const float* bn1_v  = (const float*)d_in[9];
    const float* res0_w = (const float*)d_in[10];
    const float* res0_b = (const float*)d_in[11];
    const float* w2_src = (const float*)d_in[12];
    const float* w2_dst = (const float*)d_in[13];
    const float* att2   = (const float*)d_in[14];
    const float* b2     = (const float*)d_in[15];
    const float* bn2_g  = (const float*)d_in[16];
    const float* bn2_b  = (const float*)d_in[17];
    const float* bn2_m  = (const float*)d_in[18];
    const float* bn2_v  = (const float*)d_in[19];
    const float* w3_src = (const float*)d_in[20];
    const float* w3_dst = (const float*)d_in[21];
    const float* att3   = (const float*)d_in[22];
    const float* b3     = (const float*)d_in[23];
    const float* bn3_g  = (const float*)d_in[24];
    const float* bn3_b  = (const float*)d_in[25];
    const float* bn3_m  = (const float*)d_in[26];
    const float* bn3_v  = (const float*)d_in[27];
    const float* res2_w = (const float*)d_in[28];
    const float* res2_b = (const float*)d_in[29];

    const int F_IN = 100;
    const int KP = 128;
    const int NC1 = 384, NC2 = 256, NC3 = 144;
    int N = in_sizes[0] / F_IN;
    int E = in_sizes[1] / 2;
    int Etot = E + N;
    const int* src = ei;
    const int* dst = ei + E;

    // ---- workspace layout (float units) ----
    float* ws = (float*)d_ws;
    size_t o = 0;
    _Float16* XLR = (_Float16*)(ws + o); o += (size_t)N * 128;   // [N,256] fp16
    float* B_res = ws + o; o += (size_t)N * 128;                 // residual fp32
    _Float16* A_h = (_Float16*)(ws + o); o += (size_t)N * 64;    // [N,128] fp16
    _Float16* Wb1 = (_Float16*)(ws + o); o += (size_t)KP * NC1 / 2;
    _Float16* Wb2 = (_Float16*)(ws + o); o += (size_t)KP * NC2 / 2;
    _Float16* Wb3 = (_Float16*)(ws + o); o += (size_t)KP * NC3 / 2;
    int* I_cnt  = (int*)(ws + o); o += N;
    int* I_esrc = (int*)(ws + o); o += (size_t)N * SLOT + 4;
    (void)ws_size; (void)n_in; (void)out_size;

    int mtiles = (N + 15) / 16;
    int aggGrid = (N + 3) / 4;
    int gemmGrid = (mtiles + 3) / 4;   // 1 wave per row-tile

    // 1. zero slot counters
    hipMemsetAsync(I_cnt, 0, (size_t)N * sizeof(int), stream);

    // 2. scatter (padded-slot CSR, nt stores) + prep (conv + weight pack)
    {
        int sb = (Etot + 255) / 256;
        int prepTot = N * KP + KP * (NC1 + NC2 + NC3);
        int pb = (prepTot + 255) / 256;
        prep_scat_k<<<sb + pb, 256, 0, stream>>>(
            src, dst, E, Etot, I_cnt, I_esrc, sb, x, A_h, N,
            w1_src, w1_dst, res0_w, w2_src, w2_dst, w3_src, w3_dst, res2_w,
            Wb1, Wb2, Wb3);
    }

    // 3. layer-1 GEMM (A-resident)
    mfma_gemm<4><<<gemmGrid, 256, 0, stream>>>(
        A_h, Wb1, XLR, B_res, N, NC1, 384, 256, 384, 0, 256, 128);
    // 4. layer-1 agg + epilogue
    gat_agg4_fused<<<aggGrid, 256, 0, stream>>>(
        I_cnt, I_esrc, XLR, att1, B_res, res0_b, b1,
        bn1_g, bn1_b, bn1_m, bn1_v, A_h, N, 1);

    // 5. layer-2 GEMM
    mfma_gemm<4><<<gemmGrid, 256, 0, stream>>>(
        A_h, Wb2, XLR, B_res, N, NC2, 256, 256, 256, 0, 256, 128);
    // 6. layer-2 agg + epilogue
    gat_agg4_fused<<<aggGrid, 256, 0, stream>>>(
        I_cnt, I_esrc, XLR, att2, nullptr, nullptr, b2,
        bn2_g, bn2_b, bn2_m, bn2_v, A_h, N, 2);

    // 7. layer-3 GEMM
    mfma_gemm<3><<<gemmGrid, 256, 0, stream>>>(
        A_h, Wb3, XLR, B_res, N, NC3, 141, 94, 47, 17, 128, 48);
    // 8. layer-3 agg + epilogue
    gat_agg1_fused<<<aggGrid, 256, 0, stream>>>(
        I_cnt, I_esrc, XLR, att3, B_res, res2_b, b3,
        bn3_g, bn3_b, bn3_m, bn3_v, (float*)d_out, N);
}